// Round 1
// baseline (149.980 us; speedup 1.0000x reference)
//
#include <hip/hip_runtime.h>
#include <math.h>

// CenterNetDecode: heat [8,80,192,192] f32, box [8,4,192,192] f32
// outputs (flat concat): boxes [B,H,W,4], mask [B,H,W], scores [B,H,W], center [B,H,W,2]

#define BB 8
#define CC 80
#define HH 192
#define WW 192
#define SS 8          // rows per wave strip
#define CG 4          // channel groups (= waves per block)
#define CPG (CC/CG)   // 20 channels per wave

// Kernel 1: per-pixel score = max over channels of (heat if 3x3-local-max else 0).
// Wave = 64 x-lanes; each lane loads its own column rows y0-1..y0+8 (one global
// touch per element horizontally); vertical 3-max in regs; horizontal 3-max via
// shfl of the vertical maxes; wave-edge lanes fetch halo column with masked loads.
__global__ __launch_bounds__(256) void score_kernel(const float* __restrict__ heat,
                                                    float* __restrict__ score_out) {
    const int tid  = threadIdx.x;
    const int lane = tid & 63;
    const int wv   = tid >> 6;        // channel group 0..3
    const int xc   = blockIdx.x;      // 0..2
    const int yt   = blockIdx.y;      // 0..23
    const int b    = blockIdx.z;      // 0..7
    const int x0   = xc * 64;
    const int y0   = yt * SS;
    const int x    = x0 + lane;

    __shared__ float red[CG][SS][64];

    float sc[SS];
#pragma unroll
    for (int i = 0; i < SS; ++i) sc[i] = 0.0f;

    const bool haloLane = (lane == 0) || (lane == 63);
    const int  ex   = (lane == 0) ? (x - 1) : (x + 1);
    const bool exok = haloLane && ((unsigned)ex < WW);

    for (int k = 0; k < CPG; ++k) {
        const int c = wv * CPG + k;
        const float* hp = heat + ((size_t)(b * CC + c) * HH) * WW;
        float v[SS + 2], e[SS + 2];
#pragma unroll
        for (int r = 0; r < SS + 2; ++r) {
            const int  row = y0 - 1 + r;
            const bool rok = (unsigned)row < HH;
            v[r] = rok ? hp[row * WW + x] : -INFINITY;
            e[r] = (rok && exok) ? hp[row * WW + ex] : -INFINITY;
        }
        float vm[SS], vme[SS];
#pragma unroll
        for (int i = 0; i < SS; ++i) {
            vm[i]  = fmaxf(fmaxf(v[i], v[i + 1]), v[i + 2]);
            vme[i] = fmaxf(fmaxf(e[i], e[i + 1]), e[i + 2]);
        }
#pragma unroll
        for (int i = 0; i < SS; ++i) {
            float left  = __shfl_up(vm[i], 1);
            float right = __shfl_down(vm[i], 1);
            if (lane == 0)  left  = vme[i];
            if (lane == 63) right = vme[i];
            const float hmax = fmaxf(fmaxf(left, right), vm[i]);
            const float cv   = v[i + 1];
            const float kept = (cv == hmax) ? cv : 0.0f;
            sc[i] = fmaxf(sc[i], kept);
        }
    }

#pragma unroll
    for (int i = 0; i < SS; ++i) red[wv][i][lane] = sc[i];
    __syncthreads();

    for (int j = tid; j < SS * 64; j += 256) {
        const int i = j >> 6, l = j & 63;
        const float m = fmaxf(fmaxf(red[0][i][l], red[1][i][l]),
                              fmaxf(red[2][i][l], red[3][i][l]));
        score_out[((size_t)b * HH + (y0 + i)) * WW + x0 + l] = m;
    }
}

// Kernel 2: elementwise decode. Reads raw score (written by kernel 1 into the
// scores slot of d_out), overwrites it with the masked score, writes boxes /
// mask / center.
__global__ __launch_bounds__(256) void decode_kernel(const float* __restrict__ box,
                                                     float* __restrict__ out) {
    const int NB  = BB * HH * WW;
    const int pix = blockIdx.x * 256 + threadIdx.x;
    if (pix >= NB) return;

    const int b   = pix / (HH * WW);
    const int rem = pix - b * (HH * WW);
    const int y   = rem / WW;
    const int x   = rem - y * WW;

    float* boxes  = out;
    float* maskp  = out + (size_t)4 * NB;
    float* scorep = out + (size_t)5 * NB;
    float* ctr    = out + (size_t)6 * NB;

    const float s = scorep[pix];
    const bool  m = s > 0.7f;

    const float* bp = box + (size_t)b * 4 * HH * WW + rem;
    const float dx = bp[0];
    const float dy = bp[(size_t)HH * WW];
    const float bw = bp[(size_t)2 * HH * WW];
    const float bh = bp[(size_t)3 * HH * WW];

    const float cx = ((float)x + dx) * 4.0f;
    const float cy = ((float)y + dy) * 4.0f;
    const float w4 = bw * 4.0f;
    const float h4 = bh * 4.0f;
    const float lim = 768.0f;
    const float x1 = fminf(fmaxf(cx - w4 * 0.5f, 0.0f), lim);
    const float y1 = fminf(fmaxf(cy - h4 * 0.5f, 0.0f), lim);
    const float x2 = fminf(fmaxf(cx + w4 * 0.5f, 0.0f), lim);
    const float y2 = fminf(fmaxf(cy + h4 * 0.5f, 0.0f), lim);

    float4 bo;
    bo.x = m ? x1 : 0.0f;
    bo.y = m ? y1 : 0.0f;
    bo.z = m ? (x2 - x1) : 0.0f;
    bo.w = m ? (y2 - y1) : 0.0f;
    reinterpret_cast<float4*>(boxes)[pix] = bo;

    maskp[pix]  = m ? 1.0f : 0.0f;
    scorep[pix] = m ? s : 0.0f;

    float2 cc;
    cc.x = m ? cx : 0.0f;
    cc.y = m ? cy : 0.0f;
    reinterpret_cast<float2*>(ctr)[pix] = cc;
}

extern "C" void kernel_launch(void* const* d_in, const int* in_sizes, int n_in,
                              void* d_out, int out_size, void* d_ws, size_t ws_size,
                              hipStream_t stream) {
    const float* heat = (const float*)d_in[0];
    const float* box  = (const float*)d_in[1];
    float* out = (float*)d_out;
    float* scorep = out + (size_t)5 * BB * HH * WW;

    dim3 g1(WW / 64, HH / SS, BB);   // 3 x 24 x 8
    score_kernel<<<g1, 256, 0, stream>>>(heat, scorep);

    const int NB = BB * HH * WW;     // 294912 = 1152 * 256
    decode_kernel<<<NB / 256, 256, 0, stream>>>(box, out);
}

// Round 2
// 148.262 us; speedup vs baseline: 1.0116x; 1.0116x over previous
//
#include <hip/hip_runtime.h>
#include <math.h>

// CenterNetDecode: heat [8,80,192,192] f32, box [8,4,192,192] f32
// outputs (flat concat): boxes [B,H,W,4], mask [B,H,W], scores [B,H,W], center [B,H,W,2]

#define BB 8
#define CC 80
#define HH 192
#define WW 192
#define SS 8                 // output rows per block strip
#define NBPIX (BB*HH*WW)     // 294912

// Kernel 1: score = max over channels of (heat if 3x3-window-max else 0).
// Wave = full image row: lanes 0..47 each hold float4 (cols 4l..4l+3); no
// x-halo loads (image edge pads -inf). Vertical 3-max per component in regs;
// horizontal 3-max needs only 2 shuffles per row (lane-boundary cols).
// 4 waves/block x 2 block-splits = 8 channel groups of 10; block partials of
// the channel-max go to ws, decode kernel maxes the two splits.
__global__ __launch_bounds__(256) void score_kernel(const float* __restrict__ heat,
                                                    float* __restrict__ part) {
    const int tid  = threadIdx.x;
    const int lane = tid & 63;
    const int wv   = tid >> 6;        // wave 0..3
    const int yt   = blockIdx.x;      // 0..23
    const int zs   = blockIdx.y;      // 0..1 channel-split
    const int b    = blockIdx.z;      // 0..7
    const int y0   = yt * SS;
    const bool lok = lane < 48;
    const int  col0 = lane * 4;

    __shared__ float red[4][SS][WW];  // 24 KB

    float4 sc[SS];
#pragma unroll
    for (int i = 0; i < SS; ++i) sc[i] = make_float4(0.f, 0.f, 0.f, 0.f);

    const int cbase = (zs * 4 + wv) * 10;
    const float NI = -INFINITY;

    for (int k = 0; k < 10; ++k) {
        const int c = cbase + k;
        const float* hp = heat + ((size_t)(b * CC + c) * HH) * WW;
        float4 v[SS + 2];
#pragma unroll
        for (int r = 0; r < SS + 2; ++r) {
            const int  row = y0 - 1 + r;
            const bool ok  = lok && ((unsigned)row < HH);
            v[r] = ok ? *reinterpret_cast<const float4*>(hp + row * WW + col0)
                      : make_float4(NI, NI, NI, NI);
        }
#pragma unroll
        for (int i = 0; i < SS; ++i) {
            const float4 a = v[i], m = v[i + 1], d = v[i + 2];
            float4 vm;
            vm.x = fmaxf(fmaxf(a.x, m.x), d.x);
            vm.y = fmaxf(fmaxf(a.y, m.y), d.y);
            vm.z = fmaxf(fmaxf(a.z, m.z), d.z);
            vm.w = fmaxf(fmaxf(a.w, m.w), d.w);

            float L = __shfl_up(vm.w, 1);    // left neighbor's col (4l-1)
            float R = __shfl_down(vm.x, 1);  // right neighbor's col (4l+4)
            if (lane == 0)  L = NI;          // image left edge
            if (lane >= 47) R = NI;          // image right edge / inactive

            float4 hm;
            hm.x = fmaxf(fmaxf(L,    vm.x), vm.y);
            hm.y = fmaxf(fmaxf(vm.x, vm.y), vm.z);
            hm.z = fmaxf(fmaxf(vm.y, vm.z), vm.w);
            hm.w = fmaxf(fmaxf(vm.z, vm.w), R);

            sc[i].x = fmaxf(sc[i].x, (m.x == hm.x) ? m.x : 0.0f);
            sc[i].y = fmaxf(sc[i].y, (m.y == hm.y) ? m.y : 0.0f);
            sc[i].z = fmaxf(sc[i].z, (m.z == hm.z) ? m.z : 0.0f);
            sc[i].w = fmaxf(sc[i].w, (m.w == hm.w) ? m.w : 0.0f);
        }
    }

    if (lok) {
#pragma unroll
        for (int i = 0; i < SS; ++i)
            *reinterpret_cast<float4*>(&red[wv][i][col0]) = sc[i];
    }
    __syncthreads();

    // reduce the 4 waves' channel groups, write partial (contiguous SS*WW)
    float* pp = part + ((size_t)(zs * BB + b) * HH + y0) * WW;
#pragma unroll
    for (int k = 0; k < SS * WW / 256; ++k) {   // 6 iters
        const int idx = k * 256 + tid;
        const int row = idx / WW, col = idx - row * WW;
        const float mx = fmaxf(fmaxf(red[0][row][col], red[1][row][col]),
                               fmaxf(red[2][row][col], red[3][row][col]));
        pp[idx] = mx;
    }
}

// Kernel 2: elementwise decode. score = max of the 2 block-split partials.
__global__ __launch_bounds__(256) void decode_kernel(const float* __restrict__ box,
                                                     const float* __restrict__ part,
                                                     float* __restrict__ out) {
    const int pix = blockIdx.x * 256 + threadIdx.x;
    if (pix >= NBPIX) return;

    const int b   = pix / (HH * WW);
    const int rem = pix - b * (HH * WW);
    const int y   = rem / WW;
    const int x   = rem - y * WW;

    float* boxes  = out;
    float* maskp  = out + (size_t)4 * NBPIX;
    float* scorep = out + (size_t)5 * NBPIX;
    float* ctr    = out + (size_t)6 * NBPIX;

    const float s = fmaxf(part[pix], part[NBPIX + pix]);
    const bool  m = s > 0.7f;

    const float* bp = box + (size_t)b * 4 * HH * WW + rem;
    const float dx = bp[0];
    const float dy = bp[(size_t)HH * WW];
    const float bw = bp[(size_t)2 * HH * WW];
    const float bh = bp[(size_t)3 * HH * WW];

    const float cx = ((float)x + dx) * 4.0f;
    const float cy = ((float)y + dy) * 4.0f;
    const float w4 = bw * 4.0f;
    const float h4 = bh * 4.0f;
    const float lim = 768.0f;
    const float x1 = fminf(fmaxf(cx - w4 * 0.5f, 0.0f), lim);
    const float y1 = fminf(fmaxf(cy - h4 * 0.5f, 0.0f), lim);
    const float x2 = fminf(fmaxf(cx + w4 * 0.5f, 0.0f), lim);
    const float y2 = fminf(fmaxf(cy + h4 * 0.5f, 0.0f), lim);

    float4 bo;
    bo.x = m ? x1 : 0.0f;
    bo.y = m ? y1 : 0.0f;
    bo.z = m ? (x2 - x1) : 0.0f;
    bo.w = m ? (y2 - y1) : 0.0f;
    reinterpret_cast<float4*>(boxes)[pix] = bo;

    maskp[pix]  = m ? 1.0f : 0.0f;
    scorep[pix] = m ? s : 0.0f;

    float2 cc;
    cc.x = m ? cx : 0.0f;
    cc.y = m ? cy : 0.0f;
    reinterpret_cast<float2*>(ctr)[pix] = cc;
}

extern "C" void kernel_launch(void* const* d_in, const int* in_sizes, int n_in,
                              void* d_out, int out_size, void* d_ws, size_t ws_size,
                              hipStream_t stream) {
    const float* heat = (const float*)d_in[0];
    const float* box  = (const float*)d_in[1];
    float* out  = (float*)d_out;
    float* part = (float*)d_ws;     // 2 * NBPIX floats = 2.36 MB

    dim3 g1(HH / SS, 2, BB);        // 24 x 2 x 8 = 384 blocks
    score_kernel<<<g1, 256, 0, stream>>>(heat, part);

    decode_kernel<<<NBPIX / 256, 256, 0, stream>>>(box, part, out);
}